// Round 13
// baseline (115.666 us; speedup 1.0000x reference)
//
#include <hip/hip_runtime.h>

typedef float f32x4 __attribute__((ext_vector_type(4)));
typedef __bf16 bf16x8 __attribute__((ext_vector_type(8)));

__device__ __forceinline__ unsigned short f2bf(float f) {
  unsigned u = __builtin_bit_cast(unsigned, f);
  u = (u + 0x7FFFu + ((u >> 16) & 1u)) >> 16;
  return (unsigned short)u;
}

__device__ __forceinline__ f32x4 MFMA16(uint4 a, uint4 b, f32x4 c) {
  return __builtin_amdgcn_mfma_f32_16x16x32_bf16(
      __builtin_bit_cast(bf16x8, a), __builtin_bit_cast(bf16x8, b), c, 0, 0, 0);
}

// ---------------- weight prep: unpadded bf16 images ----------------
// wd2:  [8 kc][128 o][32 kl]      = 32768 elems
// wrs2: [3 p][4 kk][128 o][32 kl] = 49152 elems
__global__ void wn_prep(const float* __restrict__ wd, const float* __restrict__ wres,
                        const float* __restrict__ wskip, unsigned short* __restrict__ ws16) {
  int g = blockIdx.x * 256 + threadIdx.x;   // grid 320*256 = 81920 exactly
  if (g < 32768) {
    int kc = g >> 12, rem = g & 4095;
    int o = rem >> 5, kl = rem & 31;
    int k = kc * 32 + kl;
    int tap = k >> 7, i = k & 127;
    ws16[g] = f2bf(wd[(o << 8) + (i << 1) + tap]);  // w_dil (128,128,2)
  } else {
    int g2 = g - 32768;
    int pkk = g2 >> 12;           // 0..11
    int rem = g2 & 4095;
    int o = rem >> 5, kl = rem & 31;
    int p = pkk >> 2, kk = pkk & 3;
    int k = kk * 32 + kl;
    float v = (p == 0) ? wres[o * 128 + k] : wskip[((p - 1) * 128 + o) * 128 + k];
    ws16[32768 + g2] = f2bf(v);
  }
}

// ---------------- fused main kernel: ZERO barriers, wave-autonomous ----------------
// 256 threads = 4 independent waves. Each wave owns a PRIVATE 16-column t-slice
// (t0w = tile*64 + wv*16) and computes the FULL M=128 for it in both stages.
// The stage1->stage2 transpose goes through a wave-private LDS slice [16][136]
// (in-wave ds ordering via lgkmcnt; NO __syncthreads anywhere). All weights direct
// from L2-hot unpadded images (af loads are dense 1KB/instruction). The compiler
// software-pipelines loads across all phase boundaries with counted waits; waves
// never collectively drain -> memory demand stays smooth instead of bursty.
__global__ __launch_bounds__(256, 4) void wn_main(
    const float* __restrict__ x,
    const float* __restrict__ bres_g,
    const float* __restrict__ bskip_g,
    const unsigned short* __restrict__ wd2_img,
    const unsigned short* __restrict__ wrs2_img,
    float* __restrict__ out,
    float* __restrict__ skipo) {
  __shared__ unsigned short actLds[4][16 * 136];   // wave-private slices, 17408 B

  // XCD swizzle: b = w&7 -> one batch per XCD; heavy 3-pass tiles first.
  const int w = blockIdx.x;            // 0..1983
  const int b = w & 7;
  const int tile = 247 - (w >> 3);     // 247..0 (heavy first)
  const int t0 = tile * 64;

  const int tid = threadIdx.x;
  const int lane = tid & 63;
  const int wv = tid >> 6;
  const int l15 = lane & 15;
  const int lhi = lane >> 4;
  const int t0w = t0 + wv * 16;        // this wave's private t-slice

  unsigned short* actw = &actLds[wv][0];

  const float* xb_base = x + (size_t)b * (128 * 16384);

  f32x4 acc[8];
#pragma unroll
  for (int i = 0; i < 8; ++i) acc[i] = (f32x4){0.f, 0.f, 0.f, 0.f};

  // ---- stage 1: pre[o][t-slice] = [W0|W1] @ [x(t);x(t+512)], K=256, 8 chunks ----
  // B-frag lane l: x[(kc&3)*32 + lhi*8 + j][t0w + (kc>=4)*512 + l15]
#pragma unroll 2
  for (int kc = 0; kc < 8; ++kc) {
    const float* xq = xb_base + (size_t)((kc & 3) * 32 + lhi * 8) * 16384
                    + t0w + ((kc >> 2) << 9) + l15;
    float xf[8];
#pragma unroll
    for (int j = 0; j < 8; ++j) xf[j] = xq[(size_t)j * 16384];
    const unsigned short* wbase = wd2_img + (kc << 12) + lhi * 8;
    uint4 af[4];
    bf16x8 tv;
#pragma unroll
    for (int j = 0; j < 8; ++j) tv[j] = (__bf16)xf[j];
    uint4 bfr = __builtin_bit_cast(uint4, tv);
    // M half 0 (o 0..63)
#pragma unroll
    for (int mi = 0; mi < 4; ++mi)
      af[mi] = *(const uint4*)(wbase + (mi * 16 + l15) * 32);
#pragma unroll
    for (int mi = 0; mi < 4; ++mi)
      acc[mi] = MFMA16(af[mi], bfr, acc[mi]);
    // M half 1 (o 64..127)
#pragma unroll
    for (int mi = 0; mi < 4; ++mi)
      af[mi] = *(const uint4*)(wbase + ((mi + 4) * 16 + l15) * 32);
#pragma unroll
    for (int mi = 0; mi < 4; ++mi)
      acc[mi + 4] = MFMA16(af[mi], bfr, acc[mi + 4]);
  }

  // ---- activation -> wave-private actw[t=l15][o] (in-wave lgkmcnt ordering) ----
#pragma unroll
  for (int mi = 0; mi < 8; ++mi) {
    ushort4 av;
#pragma unroll
    for (int r = 0; r < 4; ++r) {
      float p = acc[mi][r];
      p = fminf(fmaxf(p, -15.f), 15.f);
      float ep = __expf(p);
      float e2 = ep * ep;
      float sg = ep * __builtin_amdgcn_rcpf(1.f + ep);
      float th = (e2 - 1.f) * __builtin_amdgcn_rcpf(e2 + 1.f);
      ((unsigned short*)&av)[r] = f2bf(th * sg);
    }
    *(ushort4*)(actw + l15 * 136 + mi * 16 + lhi * 4) = av;
  }

  // ---- stage 2: out (pass 0) and skip (passes 1,2); wave-autonomous ----
  const int npass = (tile >= 184) ? 3 : 1;
#pragma unroll 1
  for (int p = 0; p < npass; ++p) {
    f32x4 acc2[8];
#pragma unroll
    for (int i = 0; i < 8; ++i) acc2[i] = (f32x4){0.f, 0.f, 0.f, 0.f};

#pragma unroll 2
    for (int kk = 0; kk < 4; ++kk) {
      uint4 bfr = *(const uint4*)(actw + l15 * 136 + kk * 32 + lhi * 8);
      const unsigned short* wbase = wrs2_img + ((p * 4 + kk) << 12) + lhi * 8;
      uint4 af[4];
#pragma unroll
      for (int mi = 0; mi < 4; ++mi)
        af[mi] = *(const uint4*)(wbase + (mi * 16 + l15) * 32);
#pragma unroll
      for (int mi = 0; mi < 4; ++mi)
        acc2[mi] = MFMA16(af[mi], bfr, acc2[mi]);
#pragma unroll
      for (int mi = 0; mi < 4; ++mi)
        af[mi] = *(const uint4*)(wbase + ((mi + 4) * 16 + l15) * 32);
#pragma unroll
      for (int mi = 0; mi < 4; ++mi)
        acc2[mi + 4] = MFMA16(af[mi], bfr, acc2[mi + 4]);
    }

    if (p == 0) {
#pragma unroll
      for (int mi = 0; mi < 8; ++mi) {
        int o0 = mi * 16 + lhi * 4;
        int tl = t0w + l15;
#pragma unroll
        for (int r = 0; r < 4; ++r) {
          size_t row = (size_t)(b * 128 + o0 + r);
          float v = acc2[mi][r] + bres_g[o0 + r] + x[row * 16384 + 512 + tl];
          out[row * 15872 + tl] = v;
        }
      }
    } else {
#pragma unroll
      for (int mi = 0; mi < 8; ++mi) {
        int o2 = (p - 1) * 128 + mi * 16 + lhi * 4;
        int s = t0w + l15 - 11776;
#pragma unroll
        for (int r = 0; r < 4; ++r) {
          skipo[(size_t)(b * 256 + o2 + r) * 4096 + s] = acc2[mi][r] + bskip_g[o2 + r];
        }
      }
    }
  }
}

extern "C" void kernel_launch(void* const* d_in, const int* in_sizes, int n_in,
                              void* d_out, int out_size, void* d_ws, size_t ws_size,
                              hipStream_t stream) {
  const float* x      = (const float*)d_in[0];
  const float* w_dil  = (const float*)d_in[1];
  const float* w_res  = (const float*)d_in[2];
  const float* b_res  = (const float*)d_in[3];
  const float* w_skip = (const float*)d_in[4];
  const float* b_skip = (const float*)d_in[5];
  unsigned short* ws16 = (unsigned short*)d_ws;
  float* out = (float*)d_out;
  float* skipo = out + 16252928;  // 8*128*15872

  wn_prep<<<320, 256, 0, stream>>>(w_dil, w_res, w_skip, ws16);

  wn_main<<<1984, 256, 0, stream>>>(x, b_res, b_skip, ws16, ws16 + 32768, out, skipo);
}